// Round 1
// baseline (705.959 us; speedup 1.0000x reference)
//
#include <hip/hip_runtime.h>
#include <math.h>

#define C_CH       64
#define F_FRAMES   999
#define FRAME_LEN  640
#define FRAME_STEPc 320
#define N2         512      // complex FFT size (real FFT 1024)
#define NBINS      513
#define NMEL       40
#define NMFCC      13

#define TWO_PI_F 6.28318530717958647692f

__global__ __launch_bounds__(256)
void mfcc_kernel(const float* __restrict__ wave, float* __restrict__ out) {
    __shared__ float2 bufA[N2];
    __shared__ float2 bufB[N2];
    __shared__ float  costab[1024];   // cos(2*pi*j/1024)
    __shared__ float  mag[NBINS];
    __shared__ float  wArr[NBINS];
    __shared__ int    chArr[NBINS];
    __shared__ float  partial[240];
    __shared__ float  lm[NMEL];
    __shared__ float  dctm[NMFCC * NMEL];

    const int tid = threadIdx.x;
    const int wg  = blockIdx.x;
    const int c   = wg & 63;          // channel-major inner: adjacent blocks read adjacent addrs
    const int f   = wg >> 6;

    // ---- cos table (1024 roots of unity) ----
    for (int j = tid; j < 1024; j += 256)
        costab[j] = cosf((float)j * (TWO_PI_F / 1024.0f));

    // ---- mel filterbank per-bin (ch, w), replicating TF MfccMelFilterbank ----
    {
        const double mel_lo  = 1127.0 * log1p(20.0 / 700.0);
        const double mel_hi  = 1127.0 * log1p(7600.0 / 700.0);
        const double spacing = (mel_hi - mel_lo) / (NMEL + 1);
        for (int i = tid; i < NBINS; i += 256) {
            if (i < 2 || i > 486) {     // start_index=2, end_index=486 for these params
                chArr[i] = -100; wArr[i] = 0.0f;
            } else {
                double melf = 1127.0 * log1p((double)i * 15.625 / 700.0);
                int ch = 0;
                while (ch < NMEL && (mel_lo + spacing * (ch + 1)) < melf) ch++;
                ch -= 1;                // may be -1
                double w = (mel_lo + spacing * (ch + 2) - melf) / spacing;
                chArr[i] = ch;
                wArr[i]  = (float)w;
            }
        }
    }

    // ---- DCT-II matrix: sqrt(2/40)*cos(pi*k*(n+0.5)/40) ----
    for (int idx = tid; idx < NMFCC * NMEL; idx += 256) {
        int j = idx / NMEL, m = idx - j * NMEL;
        dctm[idx] = 0.223606797749978969f *
                    cosf((float)(M_PI * (double)j * ((double)m + 0.5) / (double)NMEL));
    }

    // ---- load + Hann window + pack real 1024 (zero-padded) into complex 512 ----
    {
        const long base = (long)f * FRAME_STEPc * C_CH + c;
        for (int m = tid; m < N2; m += 256) {
            int n0 = 2 * m;
            float v0 = 0.0f, v1 = 0.0f;
            if (n0 < FRAME_LEN) {
                float h0 = 0.5f - 0.5f * cosf((float)n0 * (TWO_PI_F / 640.0f));
                float h1 = 0.5f - 0.5f * cosf((float)(n0 + 1) * (TWO_PI_F / 640.0f));
                v0 = wave[base + (long)n0 * C_CH] * h0;
                v1 = wave[base + (long)(n0 + 1) * C_CH] * h1;
            }
            bufA[m] = make_float2(v0, v1);
        }
    }
    __syncthreads();

    // ---- 512-pt complex Stockham DIF FFT (autosort), 9 stages, 256 butterflies each ----
    float2* src = bufA;
    float2* dst = bufB;
    for (int stage = 0; stage < 9; ++stage) {
        const int s = 1 << stage;
        const int q = tid & (s - 1);
        const int p = tid >> stage;
        float2 a = src[tid];
        float2 b = src[tid + 256];
        const int j = p << (stage + 1);               // 1024*p/n, n = 512>>stage
        float wr = costab[j];
        float wi = -costab[(j + 768) & 1023];         // -sin
        float dr = a.x - b.x, di = a.y - b.y;
        const int o = q + (p << (stage + 1));
        dst[o]     = make_float2(a.x + b.x, a.y + b.y);
        dst[o + s] = make_float2(dr * wr - di * wi, dr * wi + di * wr);
        __syncthreads();
        float2* t = src; src = dst; dst = t;
    }
    // result Z in src, natural order

    // ---- real-FFT unpack + magnitude, k = 0..512 ----
    for (int k = tid; k < NBINS; k += 256) {
        float2 Zk = src[k & (N2 - 1)];
        float2 Zm = src[(N2 - k) & (N2 - 1)];
        float Er = 0.5f * (Zk.x + Zm.x);
        float Ei = 0.5f * (Zk.y - Zm.y);
        float Or = 0.5f * (Zk.y + Zm.y);
        float Oi = -0.5f * (Zk.x - Zm.x);
        float wr = costab[k];
        float wi = -costab[(k + 768) & 1023];
        float Xr = Er + wr * Or - wi * Oi;
        float Xi = Ei + wr * Oi + wi * Or;
        mag[k] = sqrtf(Xr * Xr + Xi * Xi);
    }
    __syncthreads();

    // ---- mel: 40 channels x 6 partial scans over bins 2..486 (broadcast LDS reads) ----
    if (tid < 240) {
        const int m    = tid % NMEL;
        const int part = tid / NMEL;
        float acc = 0.0f;
        for (int i = 2 + part; i <= 486; i += 6) {
            int   ch = chArr[i];
            float w  = wArr[i];
            float g  = mag[i];
            if (ch == m)     acc += w * g;
            if (ch + 1 == m) acc += (1.0f - w) * g;
        }
        partial[tid] = acc;
    }
    __syncthreads();
    if (tid < NMEL) {
        float s2 = partial[tid] + partial[tid + 40] + partial[tid + 80]
                 + partial[tid + 120] + partial[tid + 160] + partial[tid + 200];
        lm[tid] = logf(s2 + 1e-12f);
    }
    __syncthreads();

    // ---- DCT + clip + store ----
    if (tid < NMFCC) {
        float acc = 0.0f;
        #pragma unroll
        for (int m = 0; m < NMEL; ++m) acc += lm[m] * dctm[tid * NMEL + m];
        acc = fminf(10.0f, fmaxf(-10.0f, acc));
        out[((long)c * F_FRAMES + f) * NMFCC + tid] = acc;
    }
}

extern "C" void kernel_launch(void* const* d_in, const int* in_sizes, int n_in,
                              void* d_out, int out_size, void* d_ws, size_t ws_size,
                              hipStream_t stream) {
    const float* wave = (const float*)d_in[0];
    float* out = (float*)d_out;
    dim3 grid(C_CH * F_FRAMES);   // 63936 workgroups, one per (channel, frame)
    dim3 block(256);
    hipLaunchKernelGGL(mfcc_kernel, grid, block, 0, stream, wave, out);
}

// Round 2
// 445.269 us; speedup vs baseline: 1.5855x; 1.5855x over previous
//
#include <hip/hip_runtime.h>
#include <math.h>

#define C_CH       64
#define F_FRAMES   999
#define FRAME_LEN  640
#define FRAME_STEPc 320
#define N2         512      // complex FFT size (real FFT 1024)
#define NBINS      513
#define NMEL       40
#define NMFCC      13

#define TWO_PI_F 6.28318530717958647692f

// d_ws float layout
#define WS_COSTAB 0        // 1024
#define WS_HANN   1024     // 640
#define WS_W      1664     // 513
#define WS_CH     2177     // 513 (ints)
#define WS_DCT    2690     // 520
#define WS_TOTAL  3210

__global__ __launch_bounds__(256)
void setup_tables(float* __restrict__ ws) {
    const int tid = threadIdx.x;
    int* chArr = (int*)(ws + WS_CH);

    for (int j = tid; j < 1024; j += 256)
        ws[WS_COSTAB + j] = cosf((float)j * (TWO_PI_F / 1024.0f));

    for (int n = tid; n < FRAME_LEN; n += 256)
        ws[WS_HANN + n] = 0.5f - 0.5f * cosf((float)n * (TWO_PI_F / 640.0f));

    {
        const double mel_lo  = 1127.0 * log1p(20.0 / 700.0);
        const double mel_hi  = 1127.0 * log1p(7600.0 / 700.0);
        const double spacing = (mel_hi - mel_lo) / (NMEL + 1);
        for (int i = tid; i < NBINS; i += 256) {
            if (i < 2 || i > 486) {      // start_index=2, end_index=486 for these params
                chArr[i] = -100; ws[WS_W + i] = 0.0f;
            } else {
                double melf = 1127.0 * log1p((double)i * 15.625 / 700.0);
                int ch = 0;
                while (ch < NMEL && (mel_lo + spacing * (ch + 1)) < melf) ch++;
                ch -= 1;                 // may be -1
                double w = (mel_lo + spacing * (ch + 2) - melf) / spacing;
                chArr[i] = ch;
                ws[WS_W + i] = (float)w;
            }
        }
    }

    for (int idx = tid; idx < NMFCC * NMEL; idx += 256) {
        int j = idx / NMEL, m = idx - j * NMEL;
        ws[WS_DCT + idx] = 0.223606797749978969f *
            cosf((float)(M_PI * (double)j * ((double)m + 0.5) / (double)NMEL));
    }
}

__global__ __launch_bounds__(256)
void mfcc_kernel(const float* __restrict__ wave, const float* __restrict__ ws,
                 float* __restrict__ out) {
    __shared__ float2 bufA[N2];
    __shared__ float2 bufB[N2];
    __shared__ float  costab[1024];
    __shared__ float  mag[NBINS];
    __shared__ float  wArr[NBINS];
    __shared__ int    chArr[NBINS];
    __shared__ float  partial[240];
    __shared__ float  lm[NMEL];
    __shared__ float  dctm[NMFCC * NMEL];

    const int tid = threadIdx.x;
    const int wg  = blockIdx.x;
    const int c   = wg & 63;          // adjacent blocks read adjacent addrs
    const int f   = wg >> 6;

    // ---- stage tables: costab via float4 (256 threads x 16B), rest scalar ----
    {
        const float4* t4 = (const float4*)(ws + WS_COSTAB);
        ((float4*)costab)[tid] = t4[tid];
        for (int i = tid; i < NBINS; i += 256) {
            wArr[i]  = ws[WS_W + i];
            chArr[i] = ((const int*)(ws + WS_CH))[i];
        }
        for (int i = tid; i < NMFCC * NMEL; i += 256)
            dctm[i] = ws[WS_DCT + i];
    }

    // ---- load + Hann window + pack real 1024 (zero-padded) into complex 512 ----
    {
        const long base = (long)f * FRAME_STEPc * C_CH + c;
        for (int m = tid; m < N2; m += 256) {
            int n0 = 2 * m;
            float v0 = 0.0f, v1 = 0.0f;
            if (n0 < FRAME_LEN) {
                v0 = wave[base + (long)n0 * C_CH] * ws[WS_HANN + n0];
                v1 = wave[base + (long)(n0 + 1) * C_CH] * ws[WS_HANN + n0 + 1];
            }
            bufA[m] = make_float2(v0, v1);
        }
    }
    __syncthreads();

    // ---- 512-pt complex Stockham DIF FFT, 9 stages, 256 butterflies each ----
    float2* src = bufA;
    float2* dst = bufB;
    for (int stage = 0; stage < 9; ++stage) {
        const int s = 1 << stage;
        const int q = tid & (s - 1);
        const int p = tid >> stage;
        float2 a = src[tid];
        float2 b = src[tid + 256];
        const int j = p << (stage + 1);
        float wr = costab[j];
        float wi = -costab[(j + 768) & 1023];         // -sin
        float dr = a.x - b.x, di = a.y - b.y;
        const int o = q + (p << (stage + 1));
        dst[o]     = make_float2(a.x + b.x, a.y + b.y);
        dst[o + s] = make_float2(dr * wr - di * wi, dr * wi + di * wr);
        __syncthreads();
        float2* t = src; src = dst; dst = t;
    }

    // ---- real-FFT unpack + magnitude, k = 0..512 ----
    for (int k = tid; k < NBINS; k += 256) {
        float2 Zk = src[k & (N2 - 1)];
        float2 Zm = src[(N2 - k) & (N2 - 1)];
        float Er = 0.5f * (Zk.x + Zm.x);
        float Ei = 0.5f * (Zk.y - Zm.y);
        float Or = 0.5f * (Zk.y + Zm.y);
        float Oi = -0.5f * (Zk.x - Zm.x);
        float wr = costab[k];
        float wi = -costab[(k + 768) & 1023];
        float Xr = Er + wr * Or - wi * Oi;
        float Xi = Ei + wr * Oi + wi * Or;
        mag[k] = sqrtf(Xr * Xr + Xi * Xi);
    }
    __syncthreads();

    // ---- mel: 40 channels x 6 partial scans over bins 2..486 ----
    if (tid < 240) {
        const int m    = tid % NMEL;
        const int part = tid / NMEL;
        float acc = 0.0f;
        for (int i = 2 + part; i <= 486; i += 6) {
            int   ch = chArr[i];
            float w  = wArr[i];
            float g  = mag[i];
            if (ch == m)     acc += w * g;
            if (ch + 1 == m) acc += (1.0f - w) * g;
        }
        partial[tid] = acc;
    }
    __syncthreads();
    if (tid < NMEL) {
        float s2 = partial[tid] + partial[tid + 40] + partial[tid + 80]
                 + partial[tid + 120] + partial[tid + 160] + partial[tid + 200];
        lm[tid] = logf(s2 + 1e-12f);
    }
    __syncthreads();

    // ---- DCT + clip + store ----
    if (tid < NMFCC) {
        float acc = 0.0f;
        #pragma unroll
        for (int m = 0; m < NMEL; ++m) acc += lm[m] * dctm[tid * NMEL + m];
        acc = fminf(10.0f, fmaxf(-10.0f, acc));
        out[((long)c * F_FRAMES + f) * NMFCC + tid] = acc;
    }
}

extern "C" void kernel_launch(void* const* d_in, const int* in_sizes, int n_in,
                              void* d_out, int out_size, void* d_ws, size_t ws_size,
                              hipStream_t stream) {
    const float* wave = (const float*)d_in[0];
    float* out = (float*)d_out;
    float* ws  = (float*)d_ws;
    hipLaunchKernelGGL(setup_tables, dim3(1), dim3(256), 0, stream, ws);
    hipLaunchKernelGGL(mfcc_kernel, dim3(C_CH * F_FRAMES), dim3(256), 0, stream,
                       wave, ws, out);
}

// Round 3
// 423.560 us; speedup vs baseline: 1.6667x; 1.0513x over previous
//
#include <hip/hip_runtime.h>
#include <math.h>

#define C_CH       64
#define F_FRAMES   999
#define FRAME_LEN  640
#define FRAME_STEPc 320
#define N2         512      // complex FFT size (real FFT 1024)
#define NBINS      513
#define NMEL       40
#define NMFCC      13
#define FPB        3        // frames per block (999 = 3*333)
#define MELW_STRIDE 72

#define TWO_PI_F 6.28318530717958647692f

// d_ws float layout
#define WS_COSTAB 0        // 1024
#define WS_HANN   1024     // 640
#define WS_W      1664     // 513 (setup scratch)
#define WS_CH     2177     // 513 ints (setup scratch)
#define WS_DCT    2690     // 520
#define WS_MSTART 3210     // 40 ints
#define WS_MLEN   3250     // 40 ints
#define WS_MELW   3290     // 40*72 = 2880
#define WS_TOTAL  6170

__global__ __launch_bounds__(256)
void setup_tables(float* __restrict__ ws) {
    const int tid = threadIdx.x;
    int* chArr = (int*)(ws + WS_CH);

    for (int j = tid; j < 1024; j += 256)
        ws[WS_COSTAB + j] = cosf((float)j * (TWO_PI_F / 1024.0f));

    for (int n = tid; n < FRAME_LEN; n += 256)
        ws[WS_HANN + n] = 0.5f - 0.5f * cosf((float)n * (TWO_PI_F / 640.0f));

    const double mel_lo  = 1127.0 * log1p(20.0 / 700.0);
    const double mel_hi  = 1127.0 * log1p(7600.0 / 700.0);
    const double spacing = (mel_hi - mel_lo) / (NMEL + 1);
    for (int i = tid; i < NBINS; i += 256) {
        if (i < 2 || i > 486) {      // start_index=2, end_index=486 for these params
            chArr[i] = -100; ws[WS_W + i] = 0.0f;
        } else {
            double melf = 1127.0 * log1p((double)i * 15.625 / 700.0);
            int ch = 0;
            while (ch < NMEL && (mel_lo + spacing * (ch + 1)) < melf) ch++;
            ch -= 1;                 // may be -1
            double w = (mel_lo + spacing * (ch + 2) - melf) / spacing;
            chArr[i] = ch;
            ws[WS_W + i] = (float)w;
        }
    }

    for (int idx = tid; idx < NMFCC * NMEL; idx += 256) {
        int j = idx / NMEL, m = idx - j * NMEL;
        ws[WS_DCT + idx] = 0.223606797749978969f *
            cosf((float)(M_PI * (double)j * ((double)m + 0.5) / (double)NMEL));
    }

    __syncthreads();

    // ---- CSR mel: per-channel contiguous (start, len, weights) ----
    if (tid < NMEL) {
        const int m = tid;
        int lo = -1, hi = -1;
        for (int i = 2; i <= 486; ++i) {
            int ch = chArr[i];
            float wgt;
            bool member;
            if (ch == m)          { wgt = ws[WS_W + i];        member = true; }
            else if (ch + 1 == m) { wgt = 1.0f - ws[WS_W + i]; member = true; }
            else                  { wgt = 0.0f;                member = false; }
            if (member) {
                if (lo < 0) lo = i;
                hi = i;
                int j = i - lo;
                if (j < MELW_STRIDE) ws[WS_MELW + m * MELW_STRIDE + j] = wgt;
            }
        }
        int len = (lo >= 0) ? (hi - lo + 1) : 0;
        if (len > MELW_STRIDE) len = MELW_STRIDE;
        ((int*)(ws + WS_MSTART))[m] = (lo >= 0) ? lo : 0;
        ((int*)(ws + WS_MLEN))[m]   = len;
    }
}

__global__ __launch_bounds__(256)
void mfcc_kernel(const float* __restrict__ wave, const float* __restrict__ ws,
                 float* __restrict__ out) {
    __shared__ float2 bufA[N2];
    __shared__ float2 bufB[N2];
    __shared__ float  costab[1024];
    __shared__ float  samples[FPB * FRAME_STEPc + FRAME_STEPc];   // 1280
    __shared__ int    mstart[NMEL];
    __shared__ int    mlen[NMEL];
    __shared__ float  partial[240];
    __shared__ float  lm[NMEL];
    float* mag = (float*)bufA;   // aliased: FFT result lives in bufB when mag is written

    const int tid = threadIdx.x;
    const int wg  = blockIdx.x;
    const int c   = wg & 63;          // adjacent blocks read adjacent addrs
    const int fb  = wg >> 6;          // 0..332
    const int f0  = fb * FPB;

    // ---- stage tables ----
    ((float4*)costab)[tid] = ((const float4*)(ws + WS_COSTAB))[tid];
    if (tid < NMEL) {
        mstart[tid] = ((const int*)(ws + WS_MSTART))[tid];
        mlen[tid]   = ((const int*)(ws + WS_MLEN))[tid];
    }
    // ---- stage this block's sample range once (read-once gather) ----
    {
        const long s0 = (long)f0 * FRAME_STEPc;
        for (int i = tid; i < FPB * FRAME_STEPc + FRAME_STEPc; i += 256)
            samples[i] = wave[(s0 + i) * C_CH + c];
    }
    __syncthreads();

    const float2* hann2 = (const float2*)(ws + WS_HANN);
    const float*  melw  = ws + WS_MELW;
    const float*  dctm  = ws + WS_DCT;

    for (int fj = 0; fj < FPB; ++fj) {
        // ---- window + pack real 1024 (zero-padded) into complex 512 ----
        {
            const int off = fj * FRAME_STEPc;
            for (int m = tid; m < N2; m += 256) {
                float2 v = make_float2(0.0f, 0.0f);
                if (m < FRAME_LEN / 2) {
                    float2 h = hann2[m];
                    v.x = samples[off + 2 * m]     * h.x;
                    v.y = samples[off + 2 * m + 1] * h.y;
                }
                bufA[m] = v;
            }
        }
        __syncthreads();

        // ---- 512-pt complex Stockham DIF FFT, 9 stages ----
        float2* src = bufA;
        float2* dst = bufB;
        for (int stage = 0; stage < 9; ++stage) {
            const int s = 1 << stage;
            const int q = tid & (s - 1);
            const int p = tid >> stage;
            float2 a = src[tid];
            float2 b = src[tid + 256];
            const int j = p << (stage + 1);
            float wr = costab[j];
            float wi = -costab[(j + 768) & 1023];     // -sin
            float dr = a.x - b.x, di = a.y - b.y;
            const int o = q + (p << (stage + 1));
            dst[o]     = make_float2(a.x + b.x, a.y + b.y);
            dst[o + s] = make_float2(dr * wr - di * wi, dr * wi + di * wr);
            __syncthreads();
            float2* t = src; src = dst; dst = t;
        }
        // result in src == bufB (9 swaps); mag aliases bufA — disjoint

        // ---- real-FFT unpack + magnitude, k = 0..512 ----
        for (int k = tid; k < NBINS; k += 256) {
            float2 Zk = src[k & (N2 - 1)];
            float2 Zm = src[(N2 - k) & (N2 - 1)];
            float Er = 0.5f * (Zk.x + Zm.x);
            float Ei = 0.5f * (Zk.y - Zm.y);
            float Or = 0.5f * (Zk.y + Zm.y);
            float Oi = -0.5f * (Zk.x - Zm.x);
            float wr = costab[k];
            float wi = -costab[(k + 768) & 1023];
            float Xr = Er + wr * Or - wi * Oi;
            float Xi = Ei + wr * Oi + wi * Or;
            mag[k] = sqrtf(Xr * Xr + Xi * Xi);
        }
        __syncthreads();

        // ---- mel via CSR: 40 channels x 6 lanes ----
        if (tid < 240) {
            const int m   = tid / 6;
            const int sub = tid - m * 6;
            const int lo  = mstart[m];
            const int len = mlen[m];
            float acc = 0.0f;
            for (int j = sub; j < len; j += 6)
                acc += melw[m * MELW_STRIDE + j] * mag[lo + j];
            partial[tid] = acc;
        }
        __syncthreads();
        if (tid < NMEL) {
            const int b = tid * 6;
            float s2 = partial[b] + partial[b + 1] + partial[b + 2]
                     + partial[b + 3] + partial[b + 4] + partial[b + 5];
            lm[tid] = logf(s2 + 1e-12f);
        }
        __syncthreads();

        // ---- DCT + clip + store ----
        if (tid < NMFCC) {
            float acc = 0.0f;
            #pragma unroll
            for (int m = 0; m < NMEL; ++m) acc += lm[m] * dctm[tid * NMEL + m];
            acc = fminf(10.0f, fmaxf(-10.0f, acc));
            out[((long)c * F_FRAMES + (f0 + fj)) * NMFCC + tid] = acc;
        }
        __syncthreads();   // protect bufA (mag) and lm before next frame
    }
}

extern "C" void kernel_launch(void* const* d_in, const int* in_sizes, int n_in,
                              void* d_out, int out_size, void* d_ws, size_t ws_size,
                              hipStream_t stream) {
    const float* wave = (const float*)d_in[0];
    float* out = (float*)d_out;
    float* ws  = (float*)d_ws;
    hipLaunchKernelGGL(setup_tables, dim3(1), dim3(256), 0, stream, ws);
    hipLaunchKernelGGL(mfcc_kernel, dim3(C_CH * (F_FRAMES / FPB)), dim3(256), 0, stream,
                       wave, ws, out);
}

// Round 4
// 307.990 us; speedup vs baseline: 2.2922x; 1.3752x over previous
//
#include <hip/hip_runtime.h>
#include <math.h>

#define C_CH       64
#define F_FRAMES   999
#define TOTAL_SAMP 320000
#define FRAME_LEN  640
#define STEP       320
#define N2         512      // complex FFT size (real FFT 1024)
#define NBINS      513
#define NMEL       40
#define NMFCC      13
#define FPB        4        // frames per block, one per wave
#define NBLK       (C_CH * 250)   // 16000 blocks, divisible by 8
#define MELW_STRIDE 72
#define SPAD       576      // 512 + 64 pad float2 per wave

#define TWO_PI_F 6.28318530717958647692f

// d_ws float layout
#define WS_COSTAB 0        // 1024
#define WS_HANN   1024     // 640
#define WS_W      1664     // 513 (setup scratch)
#define WS_CH     2177     // 513 ints (setup scratch)
#define WS_DCT    2690     // 520
#define WS_MSTART 3210     // 40 ints
#define WS_MLEN   3250     // 40 ints
#define WS_MELW   3290     // 40*72 = 2880
#define WS_TOTAL  6170

__global__ __launch_bounds__(256)
void setup_tables(float* __restrict__ ws) {
    const int tid = threadIdx.x;
    int* chArr = (int*)(ws + WS_CH);

    for (int j = tid; j < 1024; j += 256)
        ws[WS_COSTAB + j] = cosf((float)j * (TWO_PI_F / 1024.0f));

    for (int n = tid; n < FRAME_LEN; n += 256)
        ws[WS_HANN + n] = 0.5f - 0.5f * cosf((float)n * (TWO_PI_F / 640.0f));

    const double mel_lo  = 1127.0 * log1p(20.0 / 700.0);
    const double mel_hi  = 1127.0 * log1p(7600.0 / 700.0);
    const double spacing = (mel_hi - mel_lo) / (NMEL + 1);
    for (int i = tid; i < NBINS; i += 256) {
        if (i < 2 || i > 486) {      // start_index=2, end_index=486 for these params
            chArr[i] = -100; ws[WS_W + i] = 0.0f;
        } else {
            double melf = 1127.0 * log1p((double)i * 15.625 / 700.0);
            int ch = 0;
            while (ch < NMEL && (mel_lo + spacing * (ch + 1)) < melf) ch++;
            ch -= 1;                 // may be -1
            double w = (mel_lo + spacing * (ch + 2) - melf) / spacing;
            chArr[i] = ch;
            ws[WS_W + i] = (float)w;
        }
    }

    for (int idx = tid; idx < NMFCC * NMEL; idx += 256) {
        int j = idx / NMEL, m = idx - j * NMEL;
        ws[WS_DCT + idx] = 0.223606797749978969f *
            cosf((float)(M_PI * (double)j * ((double)m + 0.5) / (double)NMEL));
    }

    __syncthreads();

    // ---- CSR mel: per-channel contiguous (start, len, weights) ----
    if (tid < NMEL) {
        const int m = tid;
        int lo = -1, hi = -1;
        for (int i = 2; i <= 486; ++i) {
            int ch = chArr[i];
            float wgt; bool member;
            if (ch == m)          { wgt = ws[WS_W + i];        member = true; }
            else if (ch + 1 == m) { wgt = 1.0f - ws[WS_W + i]; member = true; }
            else                  { wgt = 0.0f;                member = false; }
            if (member) {
                if (lo < 0) lo = i;
                hi = i;
                int j = i - lo;
                if (j < MELW_STRIDE) ws[WS_MELW + m * MELW_STRIDE + j] = wgt;
            }
        }
        int len = (lo >= 0) ? (hi - lo + 1) : 0;
        if (len > MELW_STRIDE) len = MELW_STRIDE;
        ((int*)(ws + WS_MSTART))[m] = (lo >= 0) ? lo : 0;
        ((int*)(ws + WS_MLEN))[m]   = len;
    }
}

__device__ __forceinline__ float2 cadd(float2 a, float2 b){ return make_float2(a.x+b.x, a.y+b.y); }
__device__ __forceinline__ float2 csub(float2 a, float2 b){ return make_float2(a.x-b.x, a.y-b.y); }
__device__ __forceinline__ float2 cmul(float2 a, float2 w){ return make_float2(a.x*w.x - a.y*w.y, a.x*w.y + a.y*w.x); }
__device__ __forceinline__ float2 mulnegi(float2 a){ return make_float2(a.y, -a.x); }   // a * (-i)

// forward 8-pt DFT in registers (DIT): out[k] = sum_r v[r] W8^{rk}
__device__ __forceinline__ void dft8(float2 v[8]) {
    const float s = 0.70710678118654752440f;
    float2 b0=cadd(v[0],v[4]), b4=csub(v[0],v[4]);
    float2 b1=cadd(v[1],v[5]), b5=csub(v[1],v[5]);
    float2 b2=cadd(v[2],v[6]), b6=csub(v[2],v[6]);
    float2 b3=cadd(v[3],v[7]), b7=csub(v[3],v[7]);
    float2 c0=cadd(b0,b2), c2=csub(b0,b2);
    float2 c1=cadd(b1,b3), c3=csub(b1,b3);
    float2 t6=mulnegi(b6);
    float2 c4=cadd(b4,t6), c6=csub(b4,t6);
    float2 t7=mulnegi(b7);
    float2 c5=cadd(b5,t7), c7=csub(b5,t7);
    float2 t3=mulnegi(c3);
    float2 w1c5 = make_float2(s*(c5.x+c5.y), s*(c5.y-c5.x));   // W8^1 * c5
    float2 w3c7 = make_float2(s*(c7.y-c7.x), -s*(c7.x+c7.y));  // W8^3 * c7
    v[0]=cadd(c0,c1);   v[4]=csub(c0,c1);
    v[2]=cadd(c2,t3);   v[6]=csub(c2,t3);
    v[1]=cadd(c4,w1c5); v[5]=csub(c4,w1c5);
    v[3]=cadd(c6,w3c7); v[7]=csub(c6,w3c7);
}

__global__ __launch_bounds__(256, 5)
void mfcc_kernel(const float* __restrict__ wave, const float* __restrict__ ws,
                 float* __restrict__ out) {
    __shared__ __align__(16) float  costab[1024];
    __shared__ __align__(16) float  samples[FPB * STEP + STEP];   // 1600
    __shared__ __align__(16) float2 fftbuf[FPB * SPAD];           // 18432 B
    __shared__ float lmall[FPB * NMEL];

    const int tid = threadIdx.x;
    // XCD-bijective swizzle: 16000 % 8 == 0; each XCD gets a contiguous wgid range
    const int b    = blockIdx.x;
    const int wgid = (b & 7) * (NBLK / 8) + (b >> 3);
    const int c    = wgid & 63;          // channel (adjacent wgids share sample lines)
    const int fb   = wgid >> 6;          // 0..249
    const int f0   = fb * FPB;
    const int w    = tid >> 6;           // wave id 0..3 (= frame slot)
    const int l    = tid & 63;           // lane

    ((float4*)costab)[tid] = ((const float4*)(ws + WS_COSTAB))[tid];

    // ---- stage this block's sample range once ----
    const int s0  = f0 * STEP;
    const int lim = min(FPB * STEP + STEP, TOTAL_SAMP - s0);
    for (int i = tid; i < lim; i += 256)
        samples[i] = wave[(size_t)(s0 + i) * C_CH + c];
    __syncthreads();
    // ---- everything below is wave-private: no block barriers ----

    const int f = f0 + w;
    if (f < F_FRAMES) {
        float2* S    = fftbuf + w * SPAD;
        float*  magf = (float*)S;            // overlaid after FFT is consumed
        float*  lm   = lmall + w * NMEL;
        const float2* samples2 = (const float2*)samples;
        const float2* hann2    = (const float2*)(ws + WS_HANN);

        float2 v[8];
        // ---- window + load: stage-1 input x[l + 64r] straight into registers ----
        #pragma unroll
        for (int r = 0; r < 8; ++r) {
            const int i = l + 64 * r;
            if (r < 5) {                      // 320 complex = 640 real samples
                float2 xv = samples2[w * 160 + i];
                float2 h  = hann2[i];
                v[r] = make_float2(xv.x * h.x, xv.y * h.y);
            } else v[r] = make_float2(0.f, 0.f);
        }

        // ---- stage 1 (Ns=1): radix-8, no twiddle ----
        dft8(v);
        #pragma unroll
        for (int k = 0; k < 8; ++k) { const int i = 8 * l + k; S[i + (i >> 3)] = v[k]; }

        // ---- stage 2 (Ns=8) ----
        #pragma unroll
        for (int r = 0; r < 8; ++r) { const int i = l + 64 * r; v[r] = S[i + (i >> 3)]; }
        {
            const int t = (l & 7) << 4;       // twiddle W64^{(l%8) r} -> idx 16*(l%8)*r
            #pragma unroll
            for (int r = 1; r < 8; ++r) {
                const int idx = (t * r) & 1023;
                float2 wv = make_float2(costab[idx], -costab[(idx + 768) & 1023]);
                v[r] = cmul(v[r], wv);
            }
        }
        dft8(v);
        {
            const int idxD = ((l >> 3) << 6) + (l & 7);
            #pragma unroll
            for (int k = 0; k < 8; ++k) { const int i = idxD + 8 * k; S[i + (i >> 3)] = v[k]; }
        }

        // ---- stage 3 (Ns=64) ----
        #pragma unroll
        for (int r = 0; r < 8; ++r) { const int i = l + 64 * r; v[r] = S[i + (i >> 3)]; }
        {
            #pragma unroll
            for (int r = 1; r < 8; ++r) {
                const int idx = (2 * l * r) & 1023;    // W512^{l r}
                float2 wv = make_float2(costab[idx], -costab[(idx + 768) & 1023]);
                v[r] = cmul(v[r], wv);
            }
        }
        dft8(v);
        #pragma unroll
        for (int k = 0; k < 8; ++k) { const int i = l + 64 * k; S[i + (i >> 3)] = v[k]; }
        // Z (natural order) now in S

        // ---- real-FFT unpack + magnitude: read ALL Z first, then overwrite S ----
        float m8[8];
        float z0x = 0.f, z0y = 0.f;
        #pragma unroll
        for (int r = 0; r < 8; ++r) {
            const int k  = l + 64 * r;
            const int ia = k & (N2 - 1);
            const int ib = (N2 - k) & (N2 - 1);
            float2 Zk = S[ia + (ia >> 3)];
            float2 Zm = S[ib + (ib >> 3)];
            if (r == 0) { z0x = Zk.x; z0y = Zk.y; }
            float Er = 0.5f * (Zk.x + Zm.x);
            float Ei = 0.5f * (Zk.y - Zm.y);
            float Or = 0.5f * (Zk.y + Zm.y);
            float Oi = -0.5f * (Zk.x - Zm.x);
            float wr = costab[k];
            float wi = -costab[(k + 768) & 1023];
            float Xr = Er + wr * Or - wi * Oi;
            float Xi = Ei + wr * Oi + wi * Or;
            m8[r] = sqrtf(Xr * Xr + Xi * Xi);
        }
        #pragma unroll
        for (int r = 0; r < 8; ++r) magf[l + 64 * r] = m8[r];
        if (l == 0) magf[512] = fabsf(z0x - z0y);   // X[512] = Z0.x - Z0.y (real)

        // ---- mel via CSR: lane m handles channel m ----
        if (l < NMEL) {
            const int lo  = ((const int*)(ws + WS_MSTART))[l];
            const int len = ((const int*)(ws + WS_MLEN))[l];
            const float* wrow = ws + WS_MELW + l * MELW_STRIDE;
            float acc = 0.0f;
            for (int j = 0; j < len; ++j) acc += wrow[j] * magf[lo + j];
            lm[l] = logf(acc + 1e-12f);
        }

        // ---- DCT + clip + store (lanes 0..12) ----
        if (l < NMFCC) {
            const float* drow = ws + WS_DCT + l * NMEL;
            float acc = 0.0f;
            #pragma unroll
            for (int m = 0; m < NMEL; ++m) acc += lm[m] * drow[m];
            acc = fminf(10.0f, fmaxf(-10.0f, acc));
            out[((size_t)c * F_FRAMES + f) * NMFCC + l] = acc;
        }
    }
}

extern "C" void kernel_launch(void* const* d_in, const int* in_sizes, int n_in,
                              void* d_out, int out_size, void* d_ws, size_t ws_size,
                              hipStream_t stream) {
    const float* wave = (const float*)d_in[0];
    float* out = (float*)d_out;
    float* ws  = (float*)d_ws;
    hipLaunchKernelGGL(setup_tables, dim3(1), dim3(256), 0, stream, ws);
    hipLaunchKernelGGL(mfcc_kernel, dim3(NBLK), dim3(256), 0, stream, wave, ws, out);
}

// Round 5
// 171.159 us; speedup vs baseline: 4.1246x; 1.7994x over previous
//
#include <hip/hip_runtime.h>
#include <math.h>

#define C_CH       64
#define F_FRAMES   999
#define TOTAL_SAMP 320000
#define FRAME_LEN  640
#define STEP       320
#define N2         512      // complex FFT size (real FFT 1024)
#define NBINS      513
#define NMEL       40
#define NMFCC      13
#define FPB        4        // frames per block, one per wave
#define NBLK       (C_CH * 250)   // 16000 blocks, divisible by 8
#define MELW_STRIDE 72
#define SPAD       576      // 512 + 64 pad float2 per wave

#define TWO_PI_F 6.28318530717958647692f

// d_ws float layout
#define WS_HANN   1024     // 640
#define WS_DCT    2690     // 520
#define WS_MSTART 3210     // 40 ints
#define WS_MLEN   3250     // 40 ints
#define WS_MELW   3290     // 40*72 = 2880
#define WS_TOTAL  6170

__global__ __launch_bounds__(256)
void setup_tables(float* __restrict__ ws) {
    __shared__ float wloc[NBINS];
    __shared__ int   chloc[NBINS];
    __shared__ int   lo_s[NMEL];
    const int tid = threadIdx.x;

    for (int n = tid; n < FRAME_LEN; n += 256)
        ws[WS_HANN + n] = 0.5f - 0.5f * cosf((float)n * (TWO_PI_F / 640.0f));

    for (int idx = tid; idx < NMFCC * NMEL; idx += 256) {
        int j = idx / NMEL, m = idx - j * NMEL;
        ws[WS_DCT + idx] = 0.223606797749978969f *
            cosf((float)(M_PI * (double)j * ((double)m + 0.5) / (double)NMEL));
    }

    // dense per-bin (ch, w), replicating TF MfccMelFilterbank
    const double mel_lo  = 1127.0 * log1p(20.0 / 700.0);
    const double mel_hi  = 1127.0 * log1p(7600.0 / 700.0);
    const double spacing = (mel_hi - mel_lo) / (NMEL + 1);
    for (int i = tid; i < NBINS; i += 256) {
        if (i < 2 || i > 486) {      // start_index=2, end_index=486
            chloc[i] = -100; wloc[i] = 0.0f;
        } else {
            double melf = 1127.0 * log1p((double)i * 15.625 / 700.0);
            int ch = 0;
            while (ch < NMEL && (mel_lo + spacing * (ch + 1)) < melf) ch++;
            ch -= 1;                 // may be -1
            chloc[i] = ch;
            wloc[i]  = (float)((mel_lo + spacing * (ch + 2) - melf) / spacing);
        }
    }
    __syncthreads();

    // per-channel [lo, hi] over LDS (channel m receives bins with ch in {m-1, m})
    if (tid < NMEL) {
        int lo = -1, hi = -1;
        for (int i = 2; i <= 486; ++i) {
            int ch = chloc[i];
            if (ch == tid || ch + 1 == tid) { if (lo < 0) lo = i; hi = i; }
        }
        int len = (lo >= 0) ? (hi - lo + 1) : 0;
        if (len > MELW_STRIDE) len = MELW_STRIDE;
        lo_s[tid] = (lo >= 0) ? lo : 0;
        ((int*)(ws + WS_MSTART))[tid] = (lo >= 0) ? lo : 0;
        ((int*)(ws + WS_MLEN))[tid]   = len;
    }
    __syncthreads();

    // scatter weights: each bin writes its <=2 contributions
    for (int i = 2 + tid; i <= 486; i += 256) {
        int ch = chloc[i]; float wgt = wloc[i];
        if (ch >= 0)
            ws[WS_MELW + ch * MELW_STRIDE + (i - lo_s[ch])] = wgt;
        if (ch >= -1 && ch + 1 < NMEL)
            ws[WS_MELW + (ch + 1) * MELW_STRIDE + (i - lo_s[ch + 1])] = 1.0f - wgt;
    }
}

__device__ __forceinline__ float2 cadd(float2 a, float2 b){ return make_float2(a.x+b.x, a.y+b.y); }
__device__ __forceinline__ float2 csub(float2 a, float2 b){ return make_float2(a.x-b.x, a.y-b.y); }
__device__ __forceinline__ float2 cmul(float2 a, float2 w){ return make_float2(a.x*w.x - a.y*w.y, a.x*w.y + a.y*w.x); }
__device__ __forceinline__ float2 mulnegi(float2 a){ return make_float2(a.y, -a.x); }   // a * (-i)

// forward 8-pt DFT in registers (DIT): out[k] = sum_r v[r] W8^{rk}
__device__ __forceinline__ void dft8(float2 v[8]) {
    const float s = 0.70710678118654752440f;
    float2 b0=cadd(v[0],v[4]), b4=csub(v[0],v[4]);
    float2 b1=cadd(v[1],v[5]), b5=csub(v[1],v[5]);
    float2 b2=cadd(v[2],v[6]), b6=csub(v[2],v[6]);
    float2 b3=cadd(v[3],v[7]), b7=csub(v[3],v[7]);
    float2 c0=cadd(b0,b2), c2=csub(b0,b2);
    float2 c1=cadd(b1,b3), c3=csub(b1,b3);
    float2 t6=mulnegi(b6);
    float2 c4=cadd(b4,t6), c6=csub(b4,t6);
    float2 t7=mulnegi(b7);
    float2 c5=cadd(b5,t7), c7=csub(b5,t7);
    float2 t3=mulnegi(c3);
    float2 w1c5 = make_float2(s*(c5.x+c5.y), s*(c5.y-c5.x));   // W8^1 * c5
    float2 w3c7 = make_float2(s*(c7.y-c7.x), -s*(c7.x+c7.y));  // W8^3 * c7
    v[0]=cadd(c0,c1);   v[4]=csub(c0,c1);
    v[2]=cadd(c2,t3);   v[6]=csub(c2,t3);
    v[1]=cadd(c4,w1c5); v[5]=csub(c4,w1c5);
    v[3]=cadd(c6,w3c7); v[7]=csub(c6,w3c7);
}

__global__ __launch_bounds__(256, 6)
void mfcc_kernel(const float* __restrict__ wave, const float* __restrict__ ws,
                 float* __restrict__ out) {
    __shared__ __align__(16) float  samples[FPB * STEP + STEP];   // 1600
    __shared__ __align__(16) float2 fftbuf[FPB * SPAD];           // 18432 B
    __shared__ float lmall[FPB * NMEL];

    const int tid = threadIdx.x;
    // XCD-bijective swizzle: 16000 % 8 == 0; each XCD gets a contiguous wgid range
    const int b    = blockIdx.x;
    const int wgid = (b & 7) * (NBLK / 8) + (b >> 3);
    const int c    = wgid & 63;          // channel (adjacent wgids share sample lines)
    const int fb   = wgid >> 6;          // 0..249
    const int f0   = fb * FPB;
    const int w    = tid >> 6;           // wave id 0..3 (= frame slot)
    const int l    = tid & 63;           // lane

    // ---- stage this block's sample range once ----
    const int s0  = f0 * STEP;
    const int lim = min(FPB * STEP + STEP, TOTAL_SAMP - s0);
    for (int i = tid; i < lim; i += 256)
        samples[i] = wave[(size_t)(s0 + i) * C_CH + c];
    __syncthreads();
    // ---- everything below is wave-private: no block barriers ----

    const int f = f0 + w;
    if (f < F_FRAMES) {
        float2* S    = fftbuf + w * SPAD;
        float*  magf = (float*)S;            // overlaid after FFT is consumed
        float*  lm   = lmall + w * NMEL;
        const float2* samples2 = (const float2*)samples;
        const float2* hann2    = (const float2*)(ws + WS_HANN);

        // per-lane twiddle bases (frame-independent): W = e^{-i theta} = (cos, -sin)
        float s2a, c2a, s3a, c3a, sua, cua;
        __sincosf((float)(l & 7) * (TWO_PI_F / 64.0f),  &s2a, &c2a);
        __sincosf((float)l       * (TWO_PI_F / 512.0f), &s3a, &c3a);
        __sincosf((float)l       * (TWO_PI_F / 1024.0f),&sua, &cua);
        const float2 b2 = make_float2(c2a, -s2a);
        const float2 b3 = make_float2(c3a, -s3a);
        const float2 bu = make_float2(cua, -sua);

        float2 v[8];
        // ---- window + load: stage-1 input x[l + 64r] straight into registers ----
        #pragma unroll
        for (int r = 0; r < 8; ++r) {
            const int i = l + 64 * r;
            if (r < 5) {                      // 320 complex = 640 real samples
                float2 xv = samples2[w * 160 + i];
                float2 h  = hann2[i];
                v[r] = make_float2(xv.x * h.x, xv.y * h.y);
            } else v[r] = make_float2(0.f, 0.f);
        }

        // ---- stage 1 (Ns=1): radix-8, no twiddle ----
        dft8(v);
        #pragma unroll
        for (int k = 0; k < 8; ++k) { const int i = 8 * l + k; S[i + (i >> 3)] = v[k]; }

        // ---- stage 2 (Ns=8): twiddle W64^{(l&7) r} via register chain ----
        #pragma unroll
        for (int r = 0; r < 8; ++r) { const int i = l + 64 * r; v[r] = S[i + (i >> 3)]; }
        {
            float2 wv = b2;
            #pragma unroll
            for (int r = 1; r < 8; ++r) { v[r] = cmul(v[r], wv); wv = cmul(wv, b2); }
        }
        dft8(v);
        {
            const int idxD = ((l >> 3) << 6) + (l & 7);
            #pragma unroll
            for (int k = 0; k < 8; ++k) { const int i = idxD + 8 * k; S[i + (i >> 3)] = v[k]; }
        }

        // ---- stage 3 (Ns=64): twiddle W512^{l r} via register chain ----
        #pragma unroll
        for (int r = 0; r < 8; ++r) { const int i = l + 64 * r; v[r] = S[i + (i >> 3)]; }
        {
            float2 wv = b3;
            #pragma unroll
            for (int r = 1; r < 8; ++r) { v[r] = cmul(v[r], wv); wv = cmul(wv, b3); }
        }
        dft8(v);
        #pragma unroll
        for (int k = 0; k < 8; ++k) { const int i = l + 64 * k; S[i + (i >> 3)] = v[k]; }
        // Z (natural order) now in S

        // ---- real-FFT unpack + magnitude: read ALL Z first, then overwrite S ----
        // W16^r = (cos(pi r/8), -sin(pi r/8))
        const float C16[8] = {1.0f, 0.923879533f, 0.707106781f, 0.382683432f,
                              0.0f, -0.382683432f, -0.707106781f, -0.923879533f};
        const float S16[8] = {0.0f, 0.382683432f, 0.707106781f, 0.923879533f,
                              1.0f, 0.923879533f, 0.707106781f, 0.382683432f};
        float m8[8];
        float z0x = 0.f, z0y = 0.f;
        #pragma unroll
        for (int r = 0; r < 8; ++r) {
            const int k  = l + 64 * r;
            const int ia = k & (N2 - 1);
            const int ib = (N2 - k) & (N2 - 1);
            float2 Zk = S[ia + (ia >> 3)];
            float2 Zm = S[ib + (ib >> 3)];
            if (r == 0) { z0x = Zk.x; z0y = Zk.y; }
            float Er = 0.5f * (Zk.x + Zm.x);
            float Ei = 0.5f * (Zk.y - Zm.y);
            float Or = 0.5f * (Zk.y + Zm.y);
            float Oi = -0.5f * (Zk.x - Zm.x);
            float2 tw = cmul(bu, make_float2(C16[r], -S16[r]));   // W1024^{l+64r}
            float Xr = Er + tw.x * Or - tw.y * Oi;
            float Xi = Ei + tw.x * Oi + tw.y * Or;
            m8[r] = sqrtf(Xr * Xr + Xi * Xi);
        }
        #pragma unroll
        for (int r = 0; r < 8; ++r) magf[l + 64 * r] = m8[r];
        if (l == 0) magf[512] = fabsf(z0x - z0y);   // X[512] = Z0.x - Z0.y (real)

        // ---- mel via CSR: lane m handles channel m ----
        if (l < NMEL) {
            const int lo  = ((const int*)(ws + WS_MSTART))[l];
            const int len = ((const int*)(ws + WS_MLEN))[l];
            const float* wrow = ws + WS_MELW + l * MELW_STRIDE;
            float acc = 0.0f;
            for (int j = 0; j < len; ++j) acc += wrow[j] * magf[lo + j];
            lm[l] = logf(acc + 1e-12f);
        }

        // ---- DCT + clip + store (lanes 0..12) ----
        if (l < NMFCC) {
            const float* drow = ws + WS_DCT + l * NMEL;
            float acc = 0.0f;
            #pragma unroll
            for (int m = 0; m < NMEL; ++m) acc += lm[m] * drow[m];
            acc = fminf(10.0f, fmaxf(-10.0f, acc));
            out[((size_t)c * F_FRAMES + f) * NMFCC + l] = acc;
        }
    }
}

extern "C" void kernel_launch(void* const* d_in, const int* in_sizes, int n_in,
                              void* d_out, int out_size, void* d_ws, size_t ws_size,
                              hipStream_t stream) {
    const float* wave = (const float*)d_in[0];
    float* out = (float*)d_out;
    float* ws  = (float*)d_ws;
    hipLaunchKernelGGL(setup_tables, dim3(1), dim3(256), 0, stream, ws);
    hipLaunchKernelGGL(mfcc_kernel, dim3(NBLK), dim3(256), 0, stream, wave, ws, out);
}